// Round 4
// baseline (129.902 us; speedup 1.0000x reference)
//
#include <hip/hip_runtime.h>
#include <hip/hip_bf16.h>
#include <math.h>

#define CHN  12
#define H    256
#define W    256
#define HID  128
#define OUTC 9
#define PSTR 56   // perc row stride in shorts: 48 data + 8 pad (112 B -> 7-coprime slot rotation)
#define YSTR 72   // y1 row stride in shorts: 64 data + 8 pad (144 B -> +1 slot rotation/row)

typedef __attribute__((ext_vector_type(4))) float    f32x4;
typedef __attribute__((ext_vector_type(8))) short    s16x8;
typedef __attribute__((ext_vector_type(4))) unsigned u32x4;
typedef __attribute__((ext_vector_type(8))) __bf16   bf16x8;

#define MFMA16x16x32(a, b, c) \
    __builtin_amdgcn_mfma_f32_16x16x32_bf16(__builtin_bit_cast(bf16x8, (a)), \
                                            __builtin_bit_cast(bf16x8, (b)), (c), 0, 0, 0)

static __device__ __forceinline__ unsigned short bfbits(float f) {
    __hip_bfloat16 h = __float2bfloat16(f);   // RNE (prep kernel only)
    return __builtin_bit_cast(unsigned short, h);
}
static __device__ __forceinline__ float bits2f(unsigned short u) {
    __hip_bfloat16 h = __builtin_bit_cast(__hip_bfloat16, u);
    return __bfloat162float(h);
}
// round-to-nearest-away bf16 in the bit domain: high 16 bits of (u + 0x8000)
static __device__ __forceinline__ unsigned rna(float f) {
    return __builtin_bit_cast(unsigned, f) + 0x8000u;
}
// pack two rna()'d words into bf16x2 (even -> low half, odd -> high half): 1 v_perm_b32
static __device__ __forceinline__ unsigned pack2(unsigned uodd, unsigned ueven) {
    return __builtin_amdgcn_perm(uodd, ueven, 0x07060302u);
}
static __device__ __forceinline__ float fast_sqrtf(float x) {
    float r;
    asm("v_sqrt_f32 %0, %1" : "=v"(r) : "v"(x));
    return r;
}
// K-slot -> original perc column (-1 = zero pad). Slots 36..47: lap residual-lo (odd cols).
static __device__ __forceinline__ int orig_col(int s) {
    if (s < 36) return s;
    if (s < 48) return 2 * (s - 36) + 1;
    return -1;
}

// ---------------- prologue: bake weight fragments into d_ws ----------------
// ws layout:
//   [0)      a1  : ushort [16][64][8]   (mf = m*2+f; f=0 -> k 0..31, f=1 -> k 32..63; k>=48 zero)
//   [16384)  a2h : ushort [4][64][8]
//   [20480)  a2l : ushort [4][64][8]
//   [24576)  bi  : float  [8][64][4]
__global__ void prep_weights(const float* __restrict__ w1w, const float* __restrict__ w1b,
                             const float* __restrict__ w2w, unsigned short* __restrict__ wsbuf)
{
    const int t = threadIdx.x;      // 256 threads, one block
    const int l = t & 63;
    const int grp = t >> 6;
    const int row = l & 15;
    const int g4 = l >> 4;
    unsigned short* wsa1  = wsbuf;
    unsigned short* wsa2h = wsbuf + 16 * 64 * 8;
    unsigned short* wsa2l = wsa2h + 4 * 64 * 8;
    float*          wsbi  = (float*)(wsa2l + 4 * 64 * 8);

    for (int mf = grp; mf < 16; mf += 4) {
        int m = mf >> 1, f = mf & 1;
        int hid = m * 16 + row;
        for (int j = 0; j < 8; ++j) {
            int s = f * 32 + g4 * 8 + j;
            int c = orig_col(s);
            wsa1[(mf * 64 + l) * 8 + j] = (c >= 0) ? bfbits(w1w[hid * 36 + c]) : (unsigned short)0;
        }
    }
    {
        int kb = grp;
        for (int j = 0; j < 8; ++j) {
            float wv = (row < OUTC) ? w2w[row * HID + kb * 32 + g4 * 8 + j] : 0.f;
            unsigned short hi = bfbits(wv);
            wsa2h[(kb * 64 + l) * 8 + j] = hi;
            wsa2l[(kb * 64 + l) * 8 + j] = bfbits(wv - bits2f(hi));
        }
    }
    for (int m = grp; m < 8; m += 4)
        for (int r = 0; r < 4; ++r)
            wsbi[(m * 64 + l) * 4 + r] = w1b[m * 16 + g4 * 4 + r];
}

// ---------------- main fused kernel: one block per (batch,row) ----------------
__global__ __launch_bounds__(256, 4) void nca_main(
    const float* __restrict__ x, const float* __restrict__ rnd,
    const unsigned short* __restrict__ wsbuf, float* __restrict__ out)
{
    union SMem {
        struct { float2 csdd[CHN][W]; float prrow[W]; } s;  // live A..B only
        unsigned short perc[W][PSTR];                       // live C..E (28,672 B)
    };
    __shared__ SMem sm;
    __shared__ unsigned short y1h[4][16][YSTR];             // 9,216 B per-wave y1 buffer
    // total LDS = 37,888 B -> 4 blocks/CU

    const int t = threadIdx.x;
    // XCD-aware bijective swizzle: XCD k gets contiguous orig ids -> halo reuse in its L2
    const int orig = ((blockIdx.x & 7) << 9) | (blockIdx.x >> 3);
    const int h = orig & (H - 1);
    const int b = orig >> 8;
    const int hm = (h + H - 1) & (H - 1);
    const int hp = (h + 1) & (H - 1);
    const float* xb = x + (size_t)b * CHN * H * W;

    // ---- phase A: vertical separable pass (registers), write col sums/diffs ----
    float xc[CHN], csr[CHN], ddr[CHN];
    const float maskraw = rnd[((size_t)b * H + h) * W + t];   // issue early
    #pragma unroll
    for (int c = 0; c < CHN; ++c) {
        const float* xp = xb + (size_t)c * H * W;
        float v0 = xp[hm * W + t];
        float v1 = xp[h  * W + t];
        float v2 = xp[hp * W + t];
        xc[c] = v1;
        float cs = fmaf(2.f, v1, v0) + v2;
        float dd = v2 - v0;
        csr[c] = cs; ddr[c] = dd;
        sm.s.csdd[c][t] = make_float2(cs, dd);
        if (c == 3) {   // pool col-max, CLAMPED h-edges
            float cm = v1;
            if (h > 0)     cm = fmaxf(cm, v0);
            if (h < H - 1) cm = fmaxf(cm, v2);
            sm.s.prrow[t] = cm;
        }
    }
    __syncthreads();

    // ---- phase B: horizontal pass -> perc[36], pool/life/mask ----
    const int wm = (t + W - 1) & (W - 1);
    const int wp = (t + 1) & (W - 1);
    float perc[36];
    #pragma unroll
    for (int c = 0; c < CHN; ++c) {
        float2 vm = sm.s.csdd[c][wm];
        float2 vp = sm.s.csdd[c][wp];
        float gx  = vp.x - vm.x;                            // SOBEL_X
        float gy  = fmaf(2.f, ddr[c], vm.y) + vp.y;         // SOBEL_X^T
        float lap = fmaf(2.f, csr[c], vm.x + vp.x) - 16.f * xc[c];
        perc[2 * c]     = xc[c];
        perc[2 * c + 1] = lap;
        perc[24 + c]    = fast_sqrtf(fmaf(gx, gx, gy * gy) + 1e-8f);
    }
    float scale_reg;
    {
        float pool = sm.s.prrow[t];
        if (t > 0)     pool = fmaxf(pool, sm.s.prrow[wm]);   // clamped w-edges
        if (t < W - 1) pool = fmaxf(pool, sm.s.prrow[wp]);
        scale_reg = (pool > 0.1f && maskraw >= 0.5f) ? 1.f : 0.f;  // floor(r+0.5) == (r>=0.5)
    }
    const float gene0 = xc[9], gene1 = xc[10], gene2 = xc[11];
    __syncthreads();   // everyone done reading sm.s before aliasing it with perc

    // ---- phase C: bit-domain bf16 pack (RNA + v_perm), 6 granules of 16B ----
    {
        unsigned u[48];
        #pragma unroll
        for (int s = 0; s < 36; ++s) u[s] = rna(perc[s]);
        #pragma unroll
        for (int k = 0; k < 12; ++k) {
            float hif = __builtin_bit_cast(float, u[2 * k + 1] & 0xFFFF0000u);
            u[36 + k] = rna(perc[2 * k + 1] - hif);
        }
        unsigned short* prow = &sm.perc[t][0];
        #pragma unroll
        for (int g = 0; g < 6; ++g) {
            u32x4 v;
            #pragma unroll
            for (int j = 0; j < 4; ++j)
                v[j] = pack2(u[8 * g + 2 * j + 1], u[8 * g + 2 * j]);
            *(u32x4*)&prow[g * 8] = v;
        }
    }
    // perc rows for this wave's 64 pixels were written by this same wave -> no barrier.

    // ---- phase D: load prepped weight fragments (coalesced 16B/lane, L2-hot) ----
    const int l = t & 63;
    const int wv = t >> 6;
    const int p16 = l & 15;
    const int g4 = l >> 4;
    const s16x8* A1  = (const s16x8*)wsbuf;   // [16][64]
    const s16x8* A2H = A1 + 16 * 64;
    const s16x8* A2L = A2H + 4 * 64;
    const f32x4* BI  = (const f32x4*)(A2L + 4 * 64);

    s16x8 a1f[16];
    #pragma unroll
    for (int mf = 0; mf < 16; ++mf) a1f[mf] = A1[mf * 64 + l];
    s16x8 a2h[4], a2l[4];
    #pragma unroll
    for (int kb = 0; kb < 4; ++kb) { a2h[kb] = A2H[kb * 64 + l]; a2l[kb] = A2L[kb * 64 + l]; }
    f32x4 binit[8];
    #pragma unroll
    for (int m = 0; m < 8; ++m) binit[m] = BI[m * 64 + l];

    // ---- phase E: per-16-pixel tile: GEMM1 -> leaky -> y1 LDS -> GEMM2 -> store ----
    #pragma unroll 1
    for (int pt = 0; pt < 4; ++pt) {
        const int p = wv * 64 + pt * 16 + p16;
        const unsigned short* prow = &sm.perc[p][0];
        s16x8 blo = *(const s16x8*)&prow[g4 * 8];               // k 0..31
        s16x8 bhi;
        if (g4 < 2) {
            bhi = *(const s16x8*)&prow[(4 + g4) * 8];           // k 32..47
        } else {
            #pragma unroll
            for (int j = 0; j < 8; ++j) bhi[j] = 0;             // k 48..63 zero pad
        }

        unsigned short* ybase = &y1h[wv][p16][0];
        f32x4 acc2 = {0.f, 0.f, 0.f, 0.f};

        #pragma unroll
        for (int hh = 0; hh < 2; ++hh) {
            f32x4 acc[4];
            #pragma unroll
            for (int m2 = 0; m2 < 4; ++m2) acc[m2] = binit[hh * 4 + m2];
            #pragma unroll
            for (int m2 = 0; m2 < 4; ++m2) {
                acc[m2] = MFMA16x16x32(a1f[(hh * 4 + m2) * 2],     blo, acc[m2]);
                acc[m2] = MFMA16x16x32(a1f[(hh * 4 + m2) * 2 + 1], bhi, acc[m2]);
            }
            // leaky relu (exact: max(v, 0.01v)) + RNA/perm pack -> b64 write
            #pragma unroll
            for (int m2 = 0; m2 < 4; ++m2) {
                float w0 = fmaxf(acc[m2][0], 0.01f * acc[m2][0]);
                float w1 = fmaxf(acc[m2][1], 0.01f * acc[m2][1]);
                float w2 = fmaxf(acc[m2][2], 0.01f * acc[m2][2]);
                float w3 = fmaxf(acc[m2][3], 0.01f * acc[m2][3]);
                unsigned lo = pack2(rna(w1), rna(w0));
                unsigned hi = pack2(rna(w3), rna(w2));
                *(uint2*)(ybase + (2 * m2 + (g4 >> 1)) * 8 + (g4 & 1) * 4) = make_uint2(lo, hi);
            }
            #pragma unroll
            for (int kb2 = 0; kb2 < 2; ++kb2) {
                u32x4 b2 = *(const u32x4*)(ybase + (kb2 * 4 + g4) * 8);
                acc2 = MFMA16x16x32(a2h[hh * 2 + kb2], b2, acc2);
                acc2 = MFMA16x16x32(a2l[hh * 2 + kb2], b2, acc2);
            }
        }

        const float sc = __shfl(scale_reg, pt * 16 + p16, 64);
        const size_t pixbase = (size_t)b * CHN * H * W + (size_t)h * W + p;
        #pragma unroll
        for (int r = 0; r < 4; ++r) {
            int o = g4 * 4 + r;
            if (o < OUTC) {
                // x center (RNA-rounded bf16) is already in blo: slot 2*o -> element 2r
                float xhi = bits2f((unsigned short)blo[2 * r]);
                out[pixbase + (size_t)o * H * W] = fmaf(acc2[r], sc, xhi);
            }
        }
    }

    // ---- gene channels passthrough ----
    {
        size_t gidx = ((size_t)b * CHN + 9) * H * W + (size_t)h * W + t;
        out[gidx]                     = gene0;
        out[gidx + (size_t)H * W]     = gene1;
        out[gidx + 2 * (size_t)H * W] = gene2;
    }
}

extern "C" void kernel_launch(void* const* d_in, const int* in_sizes, int n_in,
                              void* d_out, int out_size, void* d_ws, size_t ws_size,
                              hipStream_t stream) {
    const float* x   = (const float*)d_in[0];
    const float* rnd = (const float*)d_in[1];
    const float* w1w = (const float*)d_in[2];
    const float* w1b = (const float*)d_in[3];
    const float* w2w = (const float*)d_in[4];
    float* out = (float*)d_out;
    unsigned short* ws = (unsigned short*)d_ws;

    prep_weights<<<dim3(1), dim3(256), 0, stream>>>(w1w, w1b, w2w, ws);
    nca_main<<<dim3(16 * 256), dim3(256), 0, stream>>>(x, rnd, ws, out);
}

// Round 5
// 54.368 us; speedup vs baseline: 2.3893x; 2.3893x over previous
//
#include <hip/hip_runtime.h>
#include <hip/hip_bf16.h>
#include <math.h>

#define CHN  12
#define H    256
#define W    256
#define HID  128
#define OUTC 9
#define PSTR 56   // perc row stride in shorts: 48 data + 8 pad (112 B -> 7-coprime slot rotation)
#define YSTR 72   // y1 row stride in shorts: 64 data + 8 pad (144 B -> +1 slot rotation/row)

typedef __attribute__((ext_vector_type(4))) float    f32x4;
typedef __attribute__((ext_vector_type(8))) short    s16x8;
typedef __attribute__((ext_vector_type(4))) unsigned u32x4;
typedef __attribute__((ext_vector_type(8))) __bf16   bf16x8;

#define MFMA16x16x32(a, b, c) \
    __builtin_amdgcn_mfma_f32_16x16x32_bf16(__builtin_bit_cast(bf16x8, (a)), \
                                            __builtin_bit_cast(bf16x8, (b)), (c), 0, 0, 0)

static __device__ __forceinline__ unsigned short bfbits(float f) {
    __hip_bfloat16 h = __float2bfloat16(f);   // RNE (prep kernel only)
    return __builtin_bit_cast(unsigned short, h);
}
static __device__ __forceinline__ float bits2f(unsigned short u) {
    __hip_bfloat16 h = __builtin_bit_cast(__hip_bfloat16, u);
    return __bfloat162float(h);
}
// round-to-nearest-away bf16 in the bit domain: high 16 bits of (u + 0x8000)
static __device__ __forceinline__ unsigned rna(float f) {
    return __builtin_bit_cast(unsigned, f) + 0x8000u;
}
// pack two rna()'d words into bf16x2 (even -> low half, odd -> high half): 1 v_perm_b32
static __device__ __forceinline__ unsigned pack2(unsigned uodd, unsigned ueven) {
    return __builtin_amdgcn_perm(uodd, ueven, 0x07060302u);
}
static __device__ __forceinline__ float fast_sqrtf(float x) {
    float r;
    asm("v_sqrt_f32 %0, %1" : "=v"(r) : "v"(x));
    return r;
}

// ---------------- prologue: bake weight fragments into d_ws ----------------
// ws layout:
//   [0)      a1 : ushort [16][64][8]  (mf = m*2+f; f=0 -> k 0..31, f=1 -> k 32..63)
//            k slots: 0..35 = w1 cols, 36..47 = same w1 col as odd col 2(s-36)+1
//            (pairs with perc residual-lo), 48 = w1b (pairs with constant 1.0), 49..63 = 0
//   [16384)  a2 : ushort [4][64][8]   (bf16 w2)
__global__ void prep_weights(const float* __restrict__ w1w, const float* __restrict__ w1b,
                             const float* __restrict__ w2w, unsigned short* __restrict__ wsbuf)
{
    const int t = threadIdx.x;      // 256 threads, one block
    const int l = t & 63;
    const int grp = t >> 6;
    const int row = l & 15;
    const int g4 = l >> 4;
    unsigned short* wsa1 = wsbuf;
    unsigned short* wsa2 = wsbuf + 16 * 64 * 8;

    for (int mf = grp; mf < 16; mf += 4) {
        int m = mf >> 1, f = mf & 1;
        int hid = m * 16 + row;
        for (int j = 0; j < 8; ++j) {
            int s = f * 32 + g4 * 8 + j;
            unsigned short v = 0;
            if (s < 36)       v = bfbits(w1w[hid * 36 + s]);
            else if (s < 48)  v = bfbits(w1w[hid * 36 + 2 * (s - 36) + 1]);  // lap residual partner
            else if (s == 48) v = bfbits(w1b[hid]);                          // bias slot
            wsa1[(mf * 64 + l) * 8 + j] = v;
        }
    }
    {
        int kb = grp;
        for (int j = 0; j < 8; ++j) {
            float wv = (row < OUTC) ? w2w[row * HID + kb * 32 + g4 * 8 + j] : 0.f;
            wsa2[(kb * 64 + l) * 8 + j] = bfbits(wv);
        }
    }
}

// ---------------- main fused kernel: one block per (batch,row) ----------------
__global__ __launch_bounds__(256, 3) void nca_main(
    const float* __restrict__ x, const float* __restrict__ rnd,
    const unsigned short* __restrict__ wsbuf, float* __restrict__ out)
{
    union SMem {
        struct { float2 csdd[CHN][W]; float prrow[W]; } s;  // live A..B only
        unsigned short perc[W][PSTR];                       // live C..E (28,672 B)
    };
    __shared__ SMem sm;
    __shared__ unsigned short y1h[4][16][YSTR];             // 9,216 B per-wave y1 buffer
    // total LDS = 37,888 B -> LDS permits 4 blocks/CU

    const int t = threadIdx.x;
    // XCD-aware bijective swizzle: XCD k gets contiguous orig ids -> halo reuse in its L2
    const int orig = ((blockIdx.x & 7) << 9) | (blockIdx.x >> 3);
    const int h = orig & (H - 1);
    const int b = orig >> 8;
    const int hm = (h + H - 1) & (H - 1);
    const int hp = (h + 1) & (H - 1);
    const float* xb = x + (size_t)b * CHN * H * W;

    // ---- phase A: vertical separable pass (registers), write col sums/diffs ----
    float xc[CHN], csr[CHN], ddr[CHN];
    const float maskraw = rnd[((size_t)b * H + h) * W + t];   // issue early
    #pragma unroll
    for (int c = 0; c < CHN; ++c) {
        const float* xp = xb + (size_t)c * H * W;
        float v0 = xp[hm * W + t];
        float v1 = xp[h  * W + t];
        float v2 = xp[hp * W + t];
        xc[c] = v1;
        float cs = fmaf(2.f, v1, v0) + v2;
        float dd = v2 - v0;
        csr[c] = cs; ddr[c] = dd;
        sm.s.csdd[c][t] = make_float2(cs, dd);
        if (c == 3) {   // pool col-max, CLAMPED h-edges
            float cm = v1;
            if (h > 0)     cm = fmaxf(cm, v0);
            if (h < H - 1) cm = fmaxf(cm, v2);
            sm.s.prrow[t] = cm;
        }
    }
    __syncthreads();

    // ---- phase B: horizontal pass -> perc[36], pool/life/mask ----
    const int wm = (t + W - 1) & (W - 1);
    const int wp = (t + 1) & (W - 1);
    float perc[36];
    #pragma unroll
    for (int c = 0; c < CHN; ++c) {
        float2 vm = sm.s.csdd[c][wm];
        float2 vp = sm.s.csdd[c][wp];
        float gx  = vp.x - vm.x;                            // SOBEL_X
        float gy  = fmaf(2.f, ddr[c], vm.y) + vp.y;         // SOBEL_X^T
        float lap = fmaf(2.f, csr[c], vm.x + vp.x) - 16.f * xc[c];
        perc[2 * c]     = xc[c];
        perc[2 * c + 1] = lap;
        perc[24 + c]    = fast_sqrtf(fmaf(gx, gx, gy * gy) + 1e-8f);
    }
    float scale_reg;
    {
        float pool = sm.s.prrow[t];
        if (t > 0)     pool = fmaxf(pool, sm.s.prrow[wm]);   // clamped w-edges
        if (t < W - 1) pool = fmaxf(pool, sm.s.prrow[wp]);
        scale_reg = (pool > 0.1f && maskraw >= 0.5f) ? 1.f : 0.f;  // floor(r+0.5) == (r>=0.5)
    }
    const float gene0 = xc[9], gene1 = xc[10], gene2 = xc[11];
    __syncthreads();   // everyone done reading sm.s before aliasing it with perc

    // ---- phase C: bit-domain bf16 pack (RNA + v_perm), 6 granules of 16B ----
    {
        unsigned u[48];
        #pragma unroll
        for (int s = 0; s < 36; ++s) u[s] = rna(perc[s]);
        #pragma unroll
        for (int k = 0; k < 12; ++k) {
            float hif = __builtin_bit_cast(float, u[2 * k + 1] & 0xFFFF0000u);
            u[36 + k] = rna(perc[2 * k + 1] - hif);
        }
        unsigned short* prow = &sm.perc[t][0];
        #pragma unroll
        for (int g = 0; g < 6; ++g) {
            u32x4 v;
            #pragma unroll
            for (int j = 0; j < 4; ++j)
                v[j] = pack2(u[8 * g + 2 * j + 1], u[8 * g + 2 * j]);
            *(u32x4*)&prow[g * 8] = v;
        }
    }
    // perc rows for this wave's 64 pixels were written by this same wave -> no barrier.

    // ---- phase D: load prepped weight fragments (coalesced 16B/lane, L2-hot) ----
    const int l = t & 63;
    const int wv = t >> 6;
    const int p16 = l & 15;
    const int g4 = l >> 4;
    const s16x8* A1 = (const s16x8*)wsbuf;   // [16][64]
    const s16x8* A2 = A1 + 16 * 64;

    s16x8 a1f[16];
    #pragma unroll
    for (int mf = 0; mf < 16; ++mf) a1f[mf] = A1[mf * 64 + l];
    s16x8 a2[4];
    #pragma unroll
    for (int kb = 0; kb < 4; ++kb) a2[kb] = A2[kb * 64 + l];

    // constant B-fragment tail: k=48 carries 1.0 (bias partner), k 49..63 zero
    s16x8 bhi_c;
    #pragma unroll
    for (int j = 0; j < 8; ++j) bhi_c[j] = 0;
    if (g4 == 2) bhi_c[0] = (short)0x3F80;   // bf16 1.0 at k=48

    // ---- phase E: per-16-pixel tile: GEMM1 -> leaky -> y1 LDS -> GEMM2 -> store ----
    #pragma unroll 1
    for (int pt = 0; pt < 4; ++pt) {
        const int p = wv * 64 + pt * 16 + p16;
        const unsigned short* prow = &sm.perc[p][0];
        s16x8 blo = *(const s16x8*)&prow[g4 * 8];               // k 0..31
        s16x8 bhi;
        if (g4 < 2) bhi = *(const s16x8*)&prow[(4 + g4) * 8];   // k 32..47
        else        bhi = bhi_c;                                // k 48..63 constants

        unsigned short* ybase = &y1h[wv][p16][0];
        f32x4 acc2 = {0.f, 0.f, 0.f, 0.f};

        #pragma unroll
        for (int hh = 0; hh < 2; ++hh) {
            f32x4 acc[4];
            #pragma unroll
            for (int m2 = 0; m2 < 4; ++m2) { acc[m2][0] = 0.f; acc[m2][1] = 0.f; acc[m2][2] = 0.f; acc[m2][3] = 0.f; }
            #pragma unroll
            for (int m2 = 0; m2 < 4; ++m2) {
                acc[m2] = MFMA16x16x32(a1f[(hh * 4 + m2) * 2],     blo, acc[m2]);
                acc[m2] = MFMA16x16x32(a1f[(hh * 4 + m2) * 2 + 1], bhi, acc[m2]);
            }
            // leaky relu (exact: max(v, 0.01v)) + RNA/perm pack -> b64 write
            #pragma unroll
            for (int m2 = 0; m2 < 4; ++m2) {
                float w0 = fmaxf(acc[m2][0], 0.01f * acc[m2][0]);
                float w1 = fmaxf(acc[m2][1], 0.01f * acc[m2][1]);
                float w2 = fmaxf(acc[m2][2], 0.01f * acc[m2][2]);
                float w3 = fmaxf(acc[m2][3], 0.01f * acc[m2][3]);
                unsigned lo = pack2(rna(w1), rna(w0));
                unsigned hi = pack2(rna(w3), rna(w2));
                *(uint2*)(ybase + (2 * m2 + (g4 >> 1)) * 8 + (g4 & 1) * 4) = make_uint2(lo, hi);
            }
            #pragma unroll
            for (int kb2 = 0; kb2 < 2; ++kb2) {
                u32x4 b2 = *(const u32x4*)(ybase + (kb2 * 4 + g4) * 8);
                acc2 = MFMA16x16x32(a2[hh * 2 + kb2], b2, acc2);
            }
        }

        const float sc = __shfl(scale_reg, pt * 16 + p16, 64);
        const size_t pixbase = (size_t)b * CHN * H * W + (size_t)h * W + p;
        #pragma unroll
        for (int r = 0; r < 4; ++r) {
            int o = g4 * 4 + r;
            if (o < OUTC) {
                // x center (RNA-rounded bf16) is already in blo: slot 2*o -> element 2r
                float xhi = bits2f((unsigned short)blo[2 * r]);
                out[pixbase + (size_t)o * H * W] = fmaf(acc2[r], sc, xhi);
            }
        }
    }

    // ---- gene channels passthrough ----
    {
        size_t gidx = ((size_t)b * CHN + 9) * H * W + (size_t)h * W + t;
        out[gidx]                     = gene0;
        out[gidx + (size_t)H * W]     = gene1;
        out[gidx + 2 * (size_t)H * W] = gene2;
    }
}

extern "C" void kernel_launch(void* const* d_in, const int* in_sizes, int n_in,
                              void* d_out, int out_size, void* d_ws, size_t ws_size,
                              hipStream_t stream) {
    const float* x   = (const float*)d_in[0];
    const float* rnd = (const float*)d_in[1];
    const float* w1w = (const float*)d_in[2];
    const float* w1b = (const float*)d_in[3];
    const float* w2w = (const float*)d_in[4];
    float* out = (float*)d_out;
    unsigned short* ws = (unsigned short*)d_ws;

    prep_weights<<<dim3(1), dim3(256), 0, stream>>>(w1w, w1b, w2w, ws);
    nca_main<<<dim3(16 * 256), dim3(256), 0, stream>>>(x, rnd, ws, out);
}